// Round 1
// baseline (2409.004 us; speedup 1.0000x reference)
//
#include <hip/hip_runtime.h>
#include <math.h>

#define NS   512   // states
#define NO   1024  // observations
#define NB   64    // batch
#define TMAX 512

typedef _Float16 h2v __attribute__((ext_vector_type(2)));

__device__ inline float wave_red_sum(float x) {
#pragma unroll
  for (int o = 32; o; o >>= 1) x += __shfl_xor(x, o, 64);
  return x;
}
__device__ inline float wave_red_max(float x) {
#pragma unroll
  for (int o = 32; o; o >>= 1) x = fmaxf(x, __shfl_xor(x, o, 64));
  return x;
}

__device__ inline float dot2(h2v a, h2v b, float c) {
#if __has_builtin(__builtin_amdgcn_fdot2)
  return __builtin_amdgcn_fdot2(a, b, c, false);
#else
  return c + (float)a.x * (float)b.x + (float)a.y * (float)b.y;
#endif
}

// P1: pi softmax -> pi_sm[512]
__global__ void k_pi(const float* __restrict__ pi, float* __restrict__ pi_sm) {
  __shared__ float red[8];
  int tid = threadIdx.x;
  float v = pi[tid];
  float m = wave_red_max(v);
  if ((tid & 63) == 0) red[tid >> 6] = m;
  __syncthreads();
  m = fmaxf(fmaxf(fmaxf(red[0], red[1]), fmaxf(red[2], red[3])),
            fmaxf(fmaxf(red[4], red[5]), fmaxf(red[6], red[7])));
  float e = expf(v - m);
  float s = wave_red_sum(e);
  __syncthreads();
  if ((tid & 63) == 0) red[tid >> 6] = s;
  __syncthreads();
  s = red[0] + red[1] + red[2] + red[3] + red[4] + red[5] + red[6] + red[7];
  pi_sm[tid] = e / s;
}

// P2: column logsumexp of A (axis 0). One thread per column. grid 8 x 64.
__global__ void k_colLse(const float* __restrict__ A, float* __restrict__ lseA) {
  int k = blockIdx.x * 64 + threadIdx.x;
  float m = -INFINITY;
  for (int i = 0; i < NS; i++) m = fmaxf(m, A[i * NS + k]);
  float s = 0.f;
  for (int i = 0; i < NS; i++) s += expf(A[i * NS + k] - m);
  lseA[k] = m + logf(s);
}

// P3: row logsumexp of E (axis 1). One block per row. grid 512 x 256.
__global__ void k_rowLseE(const float* __restrict__ E, float* __restrict__ lseE) {
  __shared__ float red[4];
  int i = blockIdx.x, tid = threadIdx.x;
  const float* row = E + i * NO;
  float a0 = row[tid], a1 = row[tid + 256], a2 = row[tid + 512], a3 = row[tid + 768];
  float m = fmaxf(fmaxf(a0, a1), fmaxf(a2, a3));
  m = wave_red_max(m);
  if ((tid & 63) == 0) red[tid >> 6] = m;
  __syncthreads();
  m = fmaxf(fmaxf(red[0], red[1]), fmaxf(red[2], red[3]));
  float s = expf(a0 - m) + expf(a1 - m) + expf(a2 - m) + expf(a3 - m);
  s = wave_red_sum(s);
  __syncthreads();
  if ((tid & 63) == 0) red[tid >> 6] = s;
  __syncthreads();
  s = red[0] + red[1] + red[2] + red[3];
  if (tid == 0) lseE[i] = m + logf(s);
}

// P4: pack A_exp = exp(A - lseA[col]) as fp16 in [kb][i][j] layout
// (kb = k/8, j = k%8): half index g = kb*4096 + i*8 + j. grid 512 x 512.
__global__ void k_pack(const float* __restrict__ A, const float* __restrict__ lseA,
                       _Float16* __restrict__ Apk) {
  int g = blockIdx.x * 512 + threadIdx.x;
  int kb = g >> 12;
  int i  = (g >> 3) & 511;
  int j  = g & 7;
  int k  = kb * 8 + j;
  Apk[g] = (_Float16)expf(A[i * NS + k] - lseA[k]);
}

// Main: one block per batch, thread tid = state i. v kept in scaled linear
// domain (sum = 1) as fp16 in LDS; c accumulates log-normalizers.
__global__ __launch_bounds__(512) void k_fwd(
    const float* __restrict__ E, const int* __restrict__ x,
    const int* __restrict__ Tlen, const float* __restrict__ pi_sm,
    const float* __restrict__ lseE, const uint4* __restrict__ Apk,
    float* __restrict__ out) {
  __shared__ float4 vbuf[2][NS / 8];  // 8 fp16 per float4 slot
  __shared__ float red[8];
  __shared__ int xrow[TMAX];
  int b = blockIdx.x, tid = threadIdx.x;
  for (int t = tid; t < TMAX; t += 512) xrow[t] = x[b * TMAX + t];
  float pi_i  = pi_sm[tid];
  float lse_i = lseE[tid];
  const float* Erow = E + tid * NO;
  int Tb = Tlen[b];
  float c = 0.f;
  int cur = 0;
  __syncthreads();
  for (int t = 0; t < Tb; t++) {
    float acc;
    if (t == 0) {
      acc = pi_i;  // alpha0 = log_pi + em0 handled by the shared epilogue
    } else {
      acc = 0.f;
      const float4* vp = vbuf[cur];
#pragma unroll 8
      for (int kb = 0; kb < 64; kb++) {
        uint4 a = Apk[kb * NS + tid];   // 8 fp16 of A_exp[i, 8kb..8kb+7]
        float4 vv = vp[kb];             // 8 fp16 of v[8kb..8kb+7] (broadcast)
        acc = dot2(__builtin_bit_cast(h2v, a.x), __builtin_bit_cast(h2v, vv.x), acc);
        acc = dot2(__builtin_bit_cast(h2v, a.y), __builtin_bit_cast(h2v, vv.y), acc);
        acc = dot2(__builtin_bit_cast(h2v, a.z), __builtin_bit_cast(h2v, vv.z), acc);
        acc = dot2(__builtin_bit_cast(h2v, a.w), __builtin_bit_cast(h2v, vv.w), acc);
      }
    }
    float em = expf(Erow[xrow[t]] - lse_i);
    float nv = acc * em;
    // block sum of nv
    float s = wave_red_sum(nv);
    if ((tid & 63) == 0) red[tid >> 6] = s;
    __syncthreads();
    s = red[0] + red[1] + red[2] + red[3] + red[4] + red[5] + red[6] + red[7];
    c += logf(s);
    int nxt = cur ^ 1;
    ((_Float16*)vbuf[nxt])[tid] = (_Float16)(nv / s);
    __syncthreads();
    cur = nxt;
  }
  if (tid == 0) out[b] = c;
}

extern "C" void kernel_launch(void* const* d_in, const int* in_sizes, int n_in,
                              void* d_out, int out_size, void* d_ws, size_t ws_size,
                              hipStream_t stream) {
  const float* pi = (const float*)d_in[0];
  const float* A  = (const float*)d_in[1];
  const float* E  = (const float*)d_in[2];
  const int*   x  = (const int*)d_in[3];
  const int*   T  = (const int*)d_in[4];
  float* out = (float*)d_out;

  char* ws = (char*)d_ws;
  float*    pi_sm = (float*)(ws + 0);
  float*    lseA  = (float*)(ws + 2048);
  float*    lseE  = (float*)(ws + 4096);
  _Float16* Apk   = (_Float16*)(ws + 6144);  // 512*512 fp16 = 512 KB

  hipLaunchKernelGGL(k_pi,      dim3(1),   dim3(512), 0, stream, pi, pi_sm);
  hipLaunchKernelGGL(k_colLse,  dim3(8),   dim3(64),  0, stream, A, lseA);
  hipLaunchKernelGGL(k_rowLseE, dim3(512), dim3(256), 0, stream, E, lseE);
  hipLaunchKernelGGL(k_pack,    dim3(512), dim3(512), 0, stream, A, lseA, Apk);
  hipLaunchKernelGGL(k_fwd,     dim3(64),  dim3(512), 0, stream,
                     E, x, T, pi_sm, lseE, (const uint4*)Apk, out);
}

// Round 2
// 1045.985 us; speedup vs baseline: 2.3031x; 2.3031x over previous
//
#include <hip/hip_runtime.h>
#include <math.h>

#define NS   512   // states
#define NO   1024  // observations
#define NB   64    // batch
#define TMAX 512

#define QREG 48    // uint4 chunks (8 fp16 k-values each) held in VGPRs: k 0..383
#define QLDS 16    // uint4 chunks held in LDS: k 384..511

typedef _Float16 h2v __attribute__((ext_vector_type(2)));

__device__ inline float wave_red_sum(float x) {
#pragma unroll
  for (int o = 32; o; o >>= 1) x += __shfl_xor(x, o, 64);
  return x;
}
__device__ inline float wave_red_max(float x) {
#pragma unroll
  for (int o = 32; o; o >>= 1) x = fmaxf(x, __shfl_xor(x, o, 64));
  return x;
}

__device__ inline float dot2u(unsigned int a, unsigned int b, float c) {
#if __has_builtin(__builtin_amdgcn_fdot2)
  return __builtin_amdgcn_fdot2(__builtin_bit_cast(h2v, a),
                                __builtin_bit_cast(h2v, b), c, false);
#else
  h2v av = __builtin_bit_cast(h2v, a), bv = __builtin_bit_cast(h2v, b);
  return c + (float)av.x * (float)bv.x + (float)av.y * (float)bv.y;
#endif
}

// P1: pi softmax -> pi_sm[512]
__global__ void k_pi(const float* __restrict__ pi, float* __restrict__ pi_sm) {
  __shared__ float red[8];
  int tid = threadIdx.x;
  float v = pi[tid];
  float m = wave_red_max(v);
  if ((tid & 63) == 0) red[tid >> 6] = m;
  __syncthreads();
  m = fmaxf(fmaxf(fmaxf(red[0], red[1]), fmaxf(red[2], red[3])),
            fmaxf(fmaxf(red[4], red[5]), fmaxf(red[6], red[7])));
  float e = __expf(v - m);
  float s = wave_red_sum(e);
  __syncthreads();
  if ((tid & 63) == 0) red[tid >> 6] = s;
  __syncthreads();
  s = red[0] + red[1] + red[2] + red[3] + red[4] + red[5] + red[6] + red[7];
  pi_sm[tid] = e / s;
}

// P2: column logsumexp of A (axis 0). One block (256 thr) per column. grid 512.
__global__ void k_colLse(const float* __restrict__ A, float* __restrict__ lseA) {
  __shared__ float redm[4];
  __shared__ float reds[4];
  int k = blockIdx.x, tid = threadIdx.x;
  float a0 = A[tid * NS + k], a1 = A[(tid + 256) * NS + k];
  float m = wave_red_max(fmaxf(a0, a1));
  if ((tid & 63) == 0) redm[tid >> 6] = m;
  __syncthreads();
  m = fmaxf(fmaxf(redm[0], redm[1]), fmaxf(redm[2], redm[3]));
  float s = __expf(a0 - m) + __expf(a1 - m);
  s = wave_red_sum(s);
  if ((tid & 63) == 0) reds[tid >> 6] = s;
  __syncthreads();
  s = reds[0] + reds[1] + reds[2] + reds[3];
  if (tid == 0) lseA[k] = m + __logf(s);
}

// P3: row logsumexp of E (axis 1). One block per row. grid 512 x 256.
__global__ void k_rowLseE(const float* __restrict__ E, float* __restrict__ lseE) {
  __shared__ float red[4];
  int i = blockIdx.x, tid = threadIdx.x;
  const float* row = E + i * NO;
  float a0 = row[tid], a1 = row[tid + 256], a2 = row[tid + 512], a3 = row[tid + 768];
  float m = fmaxf(fmaxf(a0, a1), fmaxf(a2, a3));
  m = wave_red_max(m);
  if ((tid & 63) == 0) red[tid >> 6] = m;
  __syncthreads();
  m = fmaxf(fmaxf(red[0], red[1]), fmaxf(red[2], red[3]));
  float s = __expf(a0 - m) + __expf(a1 - m) + __expf(a2 - m) + __expf(a3 - m);
  s = wave_red_sum(s);
  __syncthreads();
  if ((tid & 63) == 0) red[tid >> 6] = s;
  __syncthreads();
  s = red[0] + red[1] + red[2] + red[3];
  if (tid == 0) lseE[i] = m + __logf(s);
}

// P4: pack A_exp = exp(A - lseA[col]) fp16 into chunk-major layout:
// uint4 chunk Aall[q*512 + i] = row i, k = 8q..8q+7. u32-granular: word
// W[(q*512+i)*4 + h] packs k = 8q+2h, 8q+2h+1. grid 256 x 512.
__global__ void k_pack(const float* __restrict__ A, const float* __restrict__ lseA,
                       unsigned int* __restrict__ W) {
  int u = blockIdx.x * 512 + threadIdx.x;   // [0, 64*512*4)
  int q = u >> 11;
  int r = u & 2047;
  int i = r >> 2;
  int h = r & 3;
  int k0 = q * 8 + h * 2;
  float e0 = __expf(A[i * NS + k0]     - lseA[k0]);
  float e1 = __expf(A[i * NS + k0 + 1] - lseA[k0 + 1]);
  h2v p;
  p.x = (_Float16)e0;
  p.y = (_Float16)e1;
  W[u] = __builtin_bit_cast(unsigned int, p);
}

// Main forward: one block per batch, thread tid = output state i.
// A row i lives entirely on-CU: 384 k-values in VGPRs + 128 in LDS.
// v (scaled linear alpha, sum=1) ping-pongs as fp16 in LDS; broadcast reads.
__global__ __launch_bounds__(512, 2) void k_fwd(
    const float* __restrict__ E, const int* __restrict__ x,
    const int* __restrict__ Tlen, const float* __restrict__ pi_sm,
    const float* __restrict__ lseE, const uint4* __restrict__ Aall,
    float* __restrict__ out) {
  __shared__ uint4 Alds[QLDS * 512];   // 131072 B, conflict-free stride-16B
  __shared__ uint4 vbuf[2][NS / 8];    // 2 KB
  __shared__ int xrow[TMAX];           // 2 KB
  __shared__ float red[8];
  int b = blockIdx.x, tid = threadIdx.x;

  // Load this row's A into registers (coalesced uint4) and LDS.
  uint4 areg[QREG];
#pragma unroll
  for (int q = 0; q < QREG; q++) areg[q] = Aall[q * 512 + tid];
#pragma unroll
  for (int q = 0; q < QLDS; q++) Alds[q * 512 + tid] = Aall[(QREG + q) * 512 + tid];

  for (int t = tid; t < TMAX; t += 512) xrow[t] = x[b * TMAX + t];

  float pi_i  = pi_sm[tid];
  float lse_i = lseE[tid];
  const float* Erow = E + tid * NO;
  int Tb = Tlen[b];
  float c = 0.f;
  int cur = 0;
  __syncthreads();

  for (int t = 0; t < Tb; t++) {
    float epre = Erow[xrow[t]];   // issued before the dot phase; latency hidden
    float acc;
    if (t == 0) {
      acc = pi_i;
    } else {
      acc = 0.f;
      const uint4* vp = vbuf[cur];
#pragma unroll
      for (int q = 0; q < QREG; q++) {
        uint4 vv = vp[q];                      // wave-uniform broadcast
        acc = dot2u(areg[q].x, vv.x, acc);
        acc = dot2u(areg[q].y, vv.y, acc);
        acc = dot2u(areg[q].z, vv.z, acc);
        acc = dot2u(areg[q].w, vv.w, acc);
      }
#pragma unroll
      for (int q = 0; q < QLDS; q++) {
        uint4 av = Alds[q * 512 + tid];        // private, conflict-free
        uint4 vv = vp[QREG + q];
        acc = dot2u(av.x, vv.x, acc);
        acc = dot2u(av.y, vv.y, acc);
        acc = dot2u(av.z, vv.z, acc);
        acc = dot2u(av.w, vv.w, acc);
      }
    }
    float em = __expf(epre - lse_i);
    float nv = acc * em;
    float s = wave_red_sum(nv);
    if ((tid & 63) == 0) red[tid >> 6] = s;
    __syncthreads();
    s = red[0] + red[1] + red[2] + red[3] + red[4] + red[5] + red[6] + red[7];
    c += __logf(s);
    float rs = __builtin_amdgcn_rcpf(s);
    int nxt = cur ^ 1;
    ((_Float16*)vbuf[nxt])[tid] = (_Float16)(nv * rs);
    __syncthreads();
    cur = nxt;
  }
  if (tid == 0) out[b] = c;
}

extern "C" void kernel_launch(void* const* d_in, const int* in_sizes, int n_in,
                              void* d_out, int out_size, void* d_ws, size_t ws_size,
                              hipStream_t stream) {
  const float* pi = (const float*)d_in[0];
  const float* A  = (const float*)d_in[1];
  const float* E  = (const float*)d_in[2];
  const int*   x  = (const int*)d_in[3];
  const int*   T  = (const int*)d_in[4];
  float* out = (float*)d_out;

  char* ws = (char*)d_ws;
  float*        pi_sm = (float*)(ws + 0);
  float*        lseA  = (float*)(ws + 2048);
  float*        lseE  = (float*)(ws + 4096);
  unsigned int* Apk   = (unsigned int*)(ws + 6144);  // 512*512 fp16 = 512 KB

  hipLaunchKernelGGL(k_pi,      dim3(1),   dim3(512), 0, stream, pi, pi_sm);
  hipLaunchKernelGGL(k_colLse,  dim3(512), dim3(256), 0, stream, A, lseA);
  hipLaunchKernelGGL(k_rowLseE, dim3(512), dim3(256), 0, stream, E, lseE);
  hipLaunchKernelGGL(k_pack,    dim3(256), dim3(512), 0, stream, A, lseA, Apk);
  hipLaunchKernelGGL(k_fwd,     dim3(64),  dim3(512), 0, stream,
                     E, x, T, pi_sm, lseE, (const uint4*)Apk, out);
}